// Round 6
// baseline (271.010 us; speedup 1.0000x reference)
//
#include <hip/hip_runtime.h>

// ---------------------------------------------------------------------------
// BidirectionalAttention: B=2, S=4096, D=768, H=6, KVH=2, HD=128 (GQA x3)
// bf16 MFMA everywhere, fp32 accum.
// R15: k_attn = R9 structure (4 waves, 32 q-rows/wave — the LDS-balanced
//      config; R14's 16 rows/wave halved FLOP/LDS-byte and stalled on the
//      LDS pipe) + double-buffered K AND V (Ks[2],Vt[2],Ps = 80 KB; 2
//      blocks/CU = 160 KB exactly). Ps is wave-local, so PV needs no
//      barrier after softmax: ONE barrier per iteration (was 2), stages
//      issued post-barrier into the idle buffer get a full iteration of
//      latency cover. l_i reduction deferred to epilogue. Other kernels
//      unchanged.
// ---------------------------------------------------------------------------

typedef __attribute__((ext_vector_type(8))) short bf16x8;   // 8 bf16 = 4 VGPRs
typedef __attribute__((ext_vector_type(4))) float floatx4;
typedef __attribute__((ext_vector_type(4))) unsigned short ushort4v;

#define MFMA16(a, b, c) __builtin_amdgcn_mfma_f32_16x16x32_bf16((a), (b), (c), 0, 0, 0)

#if __has_builtin(__builtin_amdgcn_exp2f)
#define EXP2F(x) __builtin_amdgcn_exp2f(x)
#else
#define EXP2F(x) exp2f(x)
#endif

#define GLOAD_LDS16(gptr, lptr)                                                   \
  __builtin_amdgcn_global_load_lds(                                               \
      (const __attribute__((address_space(1))) unsigned int*)(gptr),              \
      (__attribute__((address_space(3))) unsigned int*)(lptr), 16, 0, 0)

__device__ __forceinline__ unsigned short f2bf(float f) {   // RNE
  unsigned int u = __builtin_bit_cast(unsigned int, f);
  u = u + 0x7FFFu + ((u >> 16) & 1u);
  return (unsigned short)(u >> 16);
}

__device__ __forceinline__ unsigned short f2bf_fast(float f) {  // round-half-up
  unsigned int u = __builtin_bit_cast(unsigned int, f);
  return (unsigned short)((u + 0x8000u) >> 16);
}

__device__ __forceinline__ float bf2f(unsigned short v) {
  return __builtin_bit_cast(float, (unsigned int)v << 16);
}

// ---------------- convert kernels ----------------

__global__ __launch_bounds__(256) void k_cvt_x(const float* __restrict__ x,
                                               unsigned short* __restrict__ xb, int n) {
  int i = (blockIdx.x * 256 + threadIdx.x) * 4;
  if (i + 3 < n) {
    float4 v = *(const float4*)(x + i);
    xb[i + 0] = f2bf(v.x);
    xb[i + 1] = f2bf(v.y);
    xb[i + 2] = f2bf(v.z);
    xb[i + 3] = f2bf(v.w);
  }
}

// Tiled transpose+convert for all weights. grid (12 kb, 32 nb), 256 thr.
// nb 0-11: wq -> wqkvT rows 0-767 (scaled); 12-15: wk -> rows 768-1023;
// 16-19: wv -> rows 1024-1279; 20-31: wo -> woT rows 0-767.
__global__ __launch_bounds__(256) void k_cvt_w(const float* __restrict__ wq,
                                               const float* __restrict__ wk,
                                               const float* __restrict__ wv,
                                               const float* __restrict__ wo,
                                               unsigned short* __restrict__ wqkvT,
                                               unsigned short* __restrict__ woT) {
  __shared__ float T[64 * 65];
  const float QSCALE = 1.4426950408889634f * 0.08838834764831843f; // log2(e)/sqrt(128)
  const int kb = blockIdx.x, nb = blockIdx.y, tid = threadIdx.x;

  const float* src; int ld, col0; unsigned short* dst; int n0; float scale = 1.0f;
  if (nb < 12)      { src = wq; ld = 768; col0 = nb * 64;        dst = wqkvT; n0 = nb * 64; scale = QSCALE; }
  else if (nb < 16) { src = wk; ld = 256; col0 = (nb - 12) * 64; dst = wqkvT; n0 = nb * 64; }
  else if (nb < 20) { src = wv; ld = 256; col0 = (nb - 16) * 64; dst = wqkvT; n0 = nb * 64; }
  else              { src = wo; ld = 768; col0 = (nb - 20) * 64; dst = woT;   n0 = (nb - 20) * 64; }

  const int k0 = kb * 64;
  {
    int cc = tid & 63, kk0 = tid >> 6;
#pragma unroll
    for (int it = 0; it < 16; it++) {
      int kk = kk0 + it * 4;
      T[kk * 65 + cc] = src[(size_t)(k0 + kk) * ld + col0 + cc] * scale;
    }
  }
  __syncthreads();
  {
    int kk = tid & 63, nn0 = tid >> 6;
#pragma unroll
    for (int it = 0; it < 16; it++) {
      int nn = nn0 + it * 4;
      dst[(size_t)(n0 + nn) * 768 + k0 + kk] = f2bf(T[kk * 65 + nn]);
    }
  }
}

// ---------------- GEMM: C[M,N] = A[M,K] @ Bt[N,K]^T ----------------
// 128x128 tile, BK=32, double-buffered global_load_lds staging (16B DMA,
// chunk swizzle c' = c ^ (r&3) folded into the global source address).
// SPLIT_V: columns >=1024 (V projection) written TRANSPOSED to vTout.

__device__ __forceinline__ void store_out(float* C, int i, float v) { C[i] = v; }
__device__ __forceinline__ void store_out(unsigned short* C, int i, float v) { C[i] = f2bf(v); }

template <typename OUT_T, bool SPLIT_V>
__global__ __launch_bounds__(256) void k_gemm(const unsigned short* __restrict__ A, int lda,
                                              const unsigned short* __restrict__ Bt, int ldb,
                                              OUT_T* __restrict__ C, int ldc, int K,
                                              unsigned short* __restrict__ vTout) {
  __shared__ __align__(16) unsigned short As0[128 * 32];   // 8 KB each
  __shared__ __align__(16) unsigned short As1[128 * 32];
  __shared__ __align__(16) unsigned short Bs0[128 * 32];
  __shared__ __align__(16) unsigned short Bs1[128 * 32];

  const int tid = threadIdx.x;
  const int wave = tid >> 6, lane = tid & 63;
  const int quad = lane >> 4, l16 = lane & 15;
  const int wm = (wave >> 1) * 64, wn = (wave & 1) * 64;
  const int m0 = blockIdx.y * 128, n0 = blockIdx.x * 128;

  floatx4 acc[4][4] = {};

  // stage one 128x32 slice: 512 16B-chunks, 2 per thread; chunk j holds
  // row r = j>>2, col-chunk c = (j&3) ^ (r&3) (swizzle via source address)
  auto stage = [&](const unsigned short* G, int ld, int row0, int k0, unsigned short* S) {
#pragma unroll
    for (int it = 0; it < 2; it++) {
      int j = it * 256 + tid;
      int r = j >> 2, c = (j & 3) ^ (r & 3);
      GLOAD_LDS16((const char*)(G + (size_t)(row0 + r) * ld + k0 + c * 8), &S[j * 8]);
    }
  };

  const int xq = (quad ^ (l16 & 3)) * 8;   // swizzled chunk offset for frags
  auto compute = [&](const unsigned short* As, const unsigned short* Bs) {
    bf16x8 af[4], bfr[4];
#pragma unroll
    for (int mf = 0; mf < 4; mf++)
      af[mf] = *(const bf16x8*)(&As[(wm + mf * 16 + l16) * 32 + xq]);
#pragma unroll
    for (int nf = 0; nf < 4; nf++)
      bfr[nf] = *(const bf16x8*)(&Bs[(wn + nf * 16 + l16) * 32 + xq]);
#pragma unroll
    for (int mf = 0; mf < 4; mf++)
#pragma unroll
      for (int nf = 0; nf < 4; nf++)
        acc[mf][nf] = MFMA16(af[mf], bfr[nf], acc[mf][nf]);
  };

  stage(A, lda, m0, 0, As0);
  stage(Bt, ldb, n0, 0, Bs0);

  const int half = K >> 6;   // K/64 ping-pong pairs (K multiple of 64)
#pragma unroll 1
  for (int i = 0; i < half; i++) {
    __syncthreads();                       // drains DMA -> buf0
    stage(A, lda, m0, (2 * i + 1) * 32, As1);
    stage(Bt, ldb, n0, (2 * i + 1) * 32, Bs1);
    compute(As0, Bs0);
    __syncthreads();                       // drains DMA -> buf1
    if (i < half - 1) {
      stage(A, lda, m0, (2 * i + 2) * 32, As0);
      stage(Bt, ldb, n0, (2 * i + 2) * 32, Bs0);
    }
    compute(As1, Bs1);
  }

#pragma unroll
  for (int mf = 0; mf < 4; mf++)
#pragma unroll
    for (int nf = 0; nf < 4; nf++) {
      int col = n0 + wn + nf * 16 + l16;
      if (SPLIT_V && col >= 1024) {
        int cc = col - 1024;
        int kvhh = cc >> 7, d = cc & 127;
        int row0 = m0 + wm + mf * 16 + quad * 4;
        int bb = row0 >> 12, s = row0 & 4095;
        ushort4v pv;
        pv.x = f2bf(acc[mf][nf][0]);
        pv.y = f2bf(acc[mf][nf][1]);
        pv.z = f2bf(acc[mf][nf][2]);
        pv.w = f2bf(acc[mf][nf][3]);
        *(ushort4v*)(&vTout[((size_t)((bb * 2 + kvhh) * 128) + d) * 4096 + s]) = pv;
      } else {
#pragma unroll
        for (int r = 0; r < 4; r++) {
          int row = m0 + wm + mf * 16 + quad * 4 + r;
          store_out(C, row * ldc + col, acc[mf][nf][r]);
        }
      }
    }
}

// ---------------- flash attention (segmented, double-buffered K/V) ----------
// grid (S/128, H, B*NSEG); 256 thr = 4 waves; 80 KB LDS (Ks[2]+Vt[2]+Ps).
// 32 q-rows/wave (LDS-balanced: FLOP/LDS-byte ~= q_rows). Ps is WAVE-LOCAL
// (wave w writes+reads rows [32w,32w+32)) so softmax->PV needs no barrier;
// one barrier per iteration, stages issued post-barrier into the idle
// buffer have a full iteration of flight time.

#define NSEG 4

#define KS_OFF(row, c) (((row) << 7) + ((((c) ^ ((row) & 7))) << 3))
#define VS_OFF(row, c) (((row) << 6) + ((((c) ^ ((row) & 7))) << 3))

__global__ __launch_bounds__(256) void k_attn(const unsigned short* __restrict__ qkv,
                                              const unsigned short* __restrict__ vT,
                                              unsigned short* __restrict__ Opart,
                                              float* __restrict__ lpart) {
  __shared__ __align__(16) unsigned short Ks[2][64 * 128];   // 32 KB
  __shared__ __align__(16) unsigned short Vt[2][128 * 64];   // 32 KB
  __shared__ __align__(16) unsigned short Ps[128 * 64];      // 16 KB

  const int qt = blockIdx.x, h = blockIdx.y;
  const int seg = blockIdx.z >> 1, b = blockIdx.z & 1;
  const int kvh = h / 3;
  const int tid = threadIdx.x, w = tid >> 6, lane = tid & 63;
  const int quad = lane >> 4, l16 = lane & 15;

  const char* qbase = (const char*)(qkv + (size_t)(b * 4096) * 1280 + h * 128);
  const char* kbase = (const char*)(qkv + (size_t)(b * 4096) * 1280 + 768 + kvh * 128);
  const char* vtb   = (const char*)(vT + (size_t)((b * 2 + kvh) * 128) * 4096);

  bf16x8 qf[2][4];
  floatx4 acc[2][8] = {};
  float l_i[2] = {0.f, 0.f};

  // stage Q tile (128x128): rows 0-63 -> Ks[0], rows 64-127 -> Ks[1]
#pragma unroll
  for (int it = 0; it < 8; it++) {
    int cb = it * 256 + w * 64;
    int j = cb + lane;
    int r = j >> 4, c = (j & 15) ^ (r & 7);
    unsigned short* dst = (cb < 1024) ? &Ks[0][cb * 8] : &Ks[1][(cb - 1024) * 8];
    GLOAD_LDS16(qbase + (size_t)(qt * 128 + r) * 2560 + c * 16, dst);
  }
  __syncthreads();

  {
    const unsigned short* qsrc = (w < 2) ? Ks[0] : Ks[1];
    const int qr0 = (w & 1) * 32;
#pragma unroll
    for (int qg = 0; qg < 2; qg++)
#pragma unroll
      for (int dc = 0; dc < 4; dc++)
        qf[qg][dc] = *(const bf16x8*)(&qsrc[KS_OFF(qr0 + qg * 16 + l16, dc * 4 + quad)]);
  }
  __syncthreads();   // all qf reads done before K(0) overwrites Ks[0]

  auto stage_k = [&](int kt, unsigned short* dstKs) {
#pragma unroll
    for (int it = 0; it < 4; it++) {
      int cb = it * 256 + w * 64;
      int j = cb + lane;
      int r = j >> 4, c = (j & 15) ^ (r & 7);
      GLOAD_LDS16(kbase + (size_t)(kt * 64 + r) * 2560 + c * 16, &dstKs[cb * 8]);
    }
  };
  auto stage_v = [&](int kt, unsigned short* dstVt) {
#pragma unroll
    for (int it = 0; it < 4; it++) {
      int cb = it * 256 + w * 64;
      int j = cb + lane;
      int r = j >> 3, c = (j & 7) ^ (r & 7);
      GLOAD_LDS16(vtb + (size_t)r * 8192 + kt * 128 + c * 16, &dstVt[cb * 8]);
    }
  };

  const int k0 = seg * 16;
  stage_k(k0, Ks[0]);
  stage_v(k0, Vt[0]);

#pragma unroll 1
  for (int i = 0; i < 16; i++) {
    __syncthreads();   // drains stage(i) -> buf[i&1]; all waves done with buf[(i+1)&1]
    if (i < 15) {
      stage_k(k0 + i + 1, Ks[(i + 1) & 1]);   // full iteration in flight
      stage_v(k0 + i + 1, Vt[(i + 1) & 1]);
    }
    const unsigned short* Kc = Ks[i & 1];
    const unsigned short* Vc = Vt[i & 1];

    floatx4 sfr[2][4] = {};
#pragma unroll
    for (int nf = 0; nf < 4; nf++)
#pragma unroll
      for (int dc = 0; dc < 4; dc++) {
        bf16x8 kf = *(const bf16x8*)(&Kc[KS_OFF(nf * 16 + l16, dc * 4 + quad)]);
        sfr[0][nf] = MFMA16(kf, qf[0][dc], sfr[0][nf]);
        sfr[1][nf] = MFMA16(kf, qf[1][dc], sfr[1][nf]);
      }

#pragma unroll
    for (int qg = 0; qg < 2; qg++) {
      float rs = 0.f;
#pragma unroll
      for (int nf = 0; nf < 4; nf++) {
#pragma unroll
        for (int r = 0; r < 4; r++) {
          float p = EXP2F(sfr[qg][nf][r]);
          sfr[qg][nf][r] = p;
          rs += p;
        }
        int row = w * 32 + qg * 16 + l16;
        int ch = nf * 2 + (quad >> 1);
        ushort4v pw;
        pw.x = f2bf_fast(sfr[qg][nf][0]);
        pw.y = f2bf_fast(sfr[qg][nf][1]);
        pw.z = f2bf_fast(sfr[qg][nf][2]);
        pw.w = f2bf_fast(sfr[qg][nf][3]);
        *(ushort4v*)(&Ps[VS_OFF(row, ch) + (quad & 1) * 4]) = pw;
      }
      l_i[qg] += rs;             // per-lane partial; reduced in epilogue
    }

    // NO barrier: Ps rows [32w,32w+32) are written and read by wave w only;
    // lgkmcnt ordering within the wave covers the write->read dependency.
#pragma unroll
    for (int kc = 0; kc < 2; kc++) {
      bf16x8 pf0 = *(const bf16x8*)(&Ps[VS_OFF(w * 32 + l16, kc * 4 + quad)]);
      bf16x8 pf1 = *(const bf16x8*)(&Ps[VS_OFF(w * 32 + 16 + l16, kc * 4 + quad)]);
#pragma unroll
      for (int df = 0; df < 8; df++) {
        bf16x8 vf = *(const bf16x8*)(&Vc[VS_OFF(df * 16 + l16, kc * 4 + quad)]);
        acc[0][df] = MFMA16(pf0, vf, acc[0][df]);
        acc[1][df] = MFMA16(pf1, vf, acc[1][df]);
      }
    }
  }

  // epilogue: UNNORMALIZED partial (bf16) + l (fp32); reduce l across quads
#pragma unroll
  for (int qg = 0; qg < 2; qg++) {
    float lt = l_i[qg];
    lt += __shfl_xor(lt, 16, 64);
    lt += __shfl_xor(lt, 32, 64);
    if (quad == 0)
      lpart[((size_t)(seg * 2 + b) * 6 + h) * 4096 + qt * 128 + w * 32 + qg * 16 + l16] = lt;
#pragma unroll
    for (int r = 0; r < 4; r++) {
      int row = qt * 128 + w * 32 + qg * 16 + quad * 4 + r;
      unsigned short* orow =
          Opart + (size_t)seg * 8192 * 768 + (size_t)(b * 4096 + row) * 768 + h * 128;
#pragma unroll
      for (int df = 0; df < 8; df++)
        orow[df * 16 + l16] = f2bf_fast(acc[qg][df][r]);
    }
  }
}

// ---------------- segment reduce: ob = (sum_s O_s) / (sum_s l_s) ----------------
__global__ __launch_bounds__(256) void k_reduce(const unsigned short* __restrict__ Opart,
                                                const float* __restrict__ lpart,
                                                unsigned short* __restrict__ ob) {
  int idx = (blockIdx.x * 256 + threadIdx.x) * 4;   // < 8192*768
  int row = idx / 768, col = idx - row * 768;
  int h = col >> 7;
  int b = row >> 12, r = row & 4095;

  float lt = 0.f;
#pragma unroll
  for (int s = 0; s < NSEG; s++)
    lt += lpart[((size_t)(s * 2 + b) * 6 + h) * 4096 + r];
  float inv = 1.0f / lt;

  float acc0 = 0.f, acc1 = 0.f, acc2 = 0.f, acc3 = 0.f;
#pragma unroll
  for (int s = 0; s < NSEG; s++) {
    ushort4v v = *(const ushort4v*)(&Opart[(size_t)s * 8192 * 768 + idx]);
    acc0 += bf2f(v.x);
    acc1 += bf2f(v.y);
    acc2 += bf2f(v.z);
    acc3 += bf2f(v.w);
  }
  ushort4v o;
  o.x = f2bf(acc0 * inv);
  o.y = f2bf(acc1 * inv);
  o.z = f2bf(acc2 * inv);
  o.w = f2bf(acc3 * inv);
  *(ushort4v*)(&ob[idx]) = o;
}

// ---------------- launch ----------------

extern "C" void kernel_launch(void* const* d_in, const int* in_sizes, int n_in,
                              void* d_out, int out_size, void* d_ws, size_t ws_size,
                              hipStream_t stream) {
  const float* x  = (const float*)d_in[0];
  const float* wq = (const float*)d_in[1];
  const float* wk = (const float*)d_in[2];
  const float* wv = (const float*)d_in[3];
  const float* wo = (const float*)d_in[4];
  float* out = (float*)d_out;

  char* ws = (char*)d_ws;
  unsigned short* xb    = (unsigned short*)(ws);                 // 12,582,912 B
  unsigned short* wqkvT = (unsigned short*)(ws + 12582912);      //  1,966,080 B
  unsigned short* woT   = (unsigned short*)(ws + 14548992);      //  1,179,648 B
  unsigned short* qkvb  = (unsigned short*)(ws + 15728640);      // 20,971,520 B
  unsigned short* ob    = (unsigned short*)(ws + 36700160);      // 12,582,912 B
  unsigned short* Opart = (unsigned short*)(ws + 49283072);      // 50,331,648 B
  float*          lpart = (float*)(ws + 99614720);               //     786,432 B
  unsigned short* vT    = ob;   // alias: ob dead until k_reduce; vT dead after k_attn
  // total ws use: 100,401,152 B

  k_cvt_x<<<6144, 256, 0, stream>>>(x, xb, 8192 * 768);
  k_cvt_w<<<dim3(12, 32), 256, 0, stream>>>(wq, wk, wv, wo, wqkvT, woT);

  // qkv = xb @ [wq|wk|wv]; V columns written transposed to vT
  k_gemm<unsigned short, true><<<dim3(10, 64), 256, 0, stream>>>(
      xb, 768, wqkvT, 768, qkvb, 1280, 768, vT);

  // attention: 4 KV-segments, unnormalized partials (128 q-rows/block)
  k_attn<<<dim3(32, 6, 2 * NSEG), 256, 0, stream>>>(qkvb, vT, Opart, lpart);

  // merge segments + normalize -> ob (overwrites vT region after k_attn)
  k_reduce<<<6144, 256, 0, stream>>>(Opart, lpart, ob);

  // out = ob @ wo           (M=8192, K=768, N=768), fp32 out
  k_gemm<float, false><<<dim3(6, 64), 256, 0, stream>>>(ob, 768, woT, 768, out, 768, 768, nullptr);
}

// Round 7
// 259.164 us; speedup vs baseline: 1.0457x; 1.0457x over previous
//
#include <hip/hip_runtime.h>

// ---------------------------------------------------------------------------
// BidirectionalAttention: B=2, S=4096, D=768, H=6, KVH=2, HD=128 (GQA x3)
// bf16 MFMA everywhere, fp32 accum.
// R16: k_attn = R9 two-barrier staggered single-buffer schedule (proven
//      best: 124 µs) with three VALU/state cuts:
//      (a) l computed via ones-MFMA in PV (deletes 64-add rs chain + epilogue
//          shuffles; l now sums the same bf16-rounded P that PV uses),
//      (b) QK^T/softmax split into two k-halves (sfr 32->16 regs, softmax
//          interleaves with MFMA, peak live ~164 unified -> chance of
//          3 waves/SIMD naturally, no cap -> no spill risk),
//      (c) s_setprio(1) around MFMA clusters (T5, +4-7% attn measured).
//      R14 (8-wave) and R15 (single-barrier dbuf) both regressed; reverted.
// ---------------------------------------------------------------------------

typedef __attribute__((ext_vector_type(8))) short bf16x8;   // 8 bf16 = 4 VGPRs
typedef __attribute__((ext_vector_type(4))) float floatx4;
typedef __attribute__((ext_vector_type(4))) unsigned short ushort4v;

#define MFMA16(a, b, c) __builtin_amdgcn_mfma_f32_16x16x32_bf16((a), (b), (c), 0, 0, 0)

#if __has_builtin(__builtin_amdgcn_exp2f)
#define EXP2F(x) __builtin_amdgcn_exp2f(x)
#else
#define EXP2F(x) exp2f(x)
#endif

#define GLOAD_LDS16(gptr, lptr)                                                   \
  __builtin_amdgcn_global_load_lds(                                               \
      (const __attribute__((address_space(1))) unsigned int*)(gptr),              \
      (__attribute__((address_space(3))) unsigned int*)(lptr), 16, 0, 0)

__device__ __forceinline__ unsigned short f2bf(float f) {   // RNE
  unsigned int u = __builtin_bit_cast(unsigned int, f);
  u = u + 0x7FFFu + ((u >> 16) & 1u);
  return (unsigned short)(u >> 16);
}

__device__ __forceinline__ unsigned short f2bf_fast(float f) {  // round-half-up
  unsigned int u = __builtin_bit_cast(unsigned int, f);
  return (unsigned short)((u + 0x8000u) >> 16);
}

__device__ __forceinline__ float bf2f(unsigned short v) {
  return __builtin_bit_cast(float, (unsigned int)v << 16);
}

// ---------------- convert kernels ----------------

__global__ __launch_bounds__(256) void k_cvt_x(const float* __restrict__ x,
                                               unsigned short* __restrict__ xb, int n) {
  int i = (blockIdx.x * 256 + threadIdx.x) * 4;
  if (i + 3 < n) {
    float4 v = *(const float4*)(x + i);
    xb[i + 0] = f2bf(v.x);
    xb[i + 1] = f2bf(v.y);
    xb[i + 2] = f2bf(v.z);
    xb[i + 3] = f2bf(v.w);
  }
}

// Tiled transpose+convert for all weights. grid (12 kb, 32 nb), 256 thr.
// nb 0-11: wq -> wqkvT rows 0-767 (scaled); 12-15: wk -> rows 768-1023;
// 16-19: wv -> rows 1024-1279; 20-31: wo -> woT rows 0-767.
__global__ __launch_bounds__(256) void k_cvt_w(const float* __restrict__ wq,
                                               const float* __restrict__ wk,
                                               const float* __restrict__ wv,
                                               const float* __restrict__ wo,
                                               unsigned short* __restrict__ wqkvT,
                                               unsigned short* __restrict__ woT) {
  __shared__ float T[64 * 65];
  const float QSCALE = 1.4426950408889634f * 0.08838834764831843f; // log2(e)/sqrt(128)
  const int kb = blockIdx.x, nb = blockIdx.y, tid = threadIdx.x;

  const float* src; int ld, col0; unsigned short* dst; int n0; float scale = 1.0f;
  if (nb < 12)      { src = wq; ld = 768; col0 = nb * 64;        dst = wqkvT; n0 = nb * 64; scale = QSCALE; }
  else if (nb < 16) { src = wk; ld = 256; col0 = (nb - 12) * 64; dst = wqkvT; n0 = nb * 64; }
  else if (nb < 20) { src = wv; ld = 256; col0 = (nb - 16) * 64; dst = wqkvT; n0 = nb * 64; }
  else              { src = wo; ld = 768; col0 = (nb - 20) * 64; dst = woT;   n0 = (nb - 20) * 64; }

  const int k0 = kb * 64;
  {
    int cc = tid & 63, kk0 = tid >> 6;
#pragma unroll
    for (int it = 0; it < 16; it++) {
      int kk = kk0 + it * 4;
      T[kk * 65 + cc] = src[(size_t)(k0 + kk) * ld + col0 + cc] * scale;
    }
  }
  __syncthreads();
  {
    int kk = tid & 63, nn0 = tid >> 6;
#pragma unroll
    for (int it = 0; it < 16; it++) {
      int nn = nn0 + it * 4;
      dst[(size_t)(n0 + nn) * 768 + k0 + kk] = f2bf(T[kk * 65 + nn]);
    }
  }
}

// ---------------- GEMM: C[M,N] = A[M,K] @ Bt[N,K]^T ----------------
// 128x128 tile, BK=32, double-buffered global_load_lds staging (16B DMA,
// chunk swizzle c' = c ^ (r&3) folded into the global source address).
// SPLIT_V: columns >=1024 (V projection) written TRANSPOSED to vTout.

__device__ __forceinline__ void store_out(float* C, int i, float v) { C[i] = v; }
__device__ __forceinline__ void store_out(unsigned short* C, int i, float v) { C[i] = f2bf(v); }

template <typename OUT_T, bool SPLIT_V>
__global__ __launch_bounds__(256) void k_gemm(const unsigned short* __restrict__ A, int lda,
                                              const unsigned short* __restrict__ Bt, int ldb,
                                              OUT_T* __restrict__ C, int ldc, int K,
                                              unsigned short* __restrict__ vTout) {
  __shared__ __align__(16) unsigned short As0[128 * 32];   // 8 KB each
  __shared__ __align__(16) unsigned short As1[128 * 32];
  __shared__ __align__(16) unsigned short Bs0[128 * 32];
  __shared__ __align__(16) unsigned short Bs1[128 * 32];

  const int tid = threadIdx.x;
  const int wave = tid >> 6, lane = tid & 63;
  const int quad = lane >> 4, l16 = lane & 15;
  const int wm = (wave >> 1) * 64, wn = (wave & 1) * 64;
  const int m0 = blockIdx.y * 128, n0 = blockIdx.x * 128;

  floatx4 acc[4][4] = {};

  // stage one 128x32 slice: 512 16B-chunks, 2 per thread; chunk j holds
  // row r = j>>2, col-chunk c = (j&3) ^ (r&3) (swizzle via source address)
  auto stage = [&](const unsigned short* G, int ld, int row0, int k0, unsigned short* S) {
#pragma unroll
    for (int it = 0; it < 2; it++) {
      int j = it * 256 + tid;
      int r = j >> 2, c = (j & 3) ^ (r & 3);
      GLOAD_LDS16((const char*)(G + (size_t)(row0 + r) * ld + k0 + c * 8), &S[j * 8]);
    }
  };

  const int xq = (quad ^ (l16 & 3)) * 8;   // swizzled chunk offset for frags
  auto compute = [&](const unsigned short* As, const unsigned short* Bs) {
    bf16x8 af[4], bfr[4];
#pragma unroll
    for (int mf = 0; mf < 4; mf++)
      af[mf] = *(const bf16x8*)(&As[(wm + mf * 16 + l16) * 32 + xq]);
#pragma unroll
    for (int nf = 0; nf < 4; nf++)
      bfr[nf] = *(const bf16x8*)(&Bs[(wn + nf * 16 + l16) * 32 + xq]);
#pragma unroll
    for (int mf = 0; mf < 4; mf++)
#pragma unroll
      for (int nf = 0; nf < 4; nf++)
        acc[mf][nf] = MFMA16(af[mf], bfr[nf], acc[mf][nf]);
  };

  stage(A, lda, m0, 0, As0);
  stage(Bt, ldb, n0, 0, Bs0);

  const int half = K >> 6;   // K/64 ping-pong pairs (K multiple of 64)
#pragma unroll 1
  for (int i = 0; i < half; i++) {
    __syncthreads();                       // drains DMA -> buf0
    stage(A, lda, m0, (2 * i + 1) * 32, As1);
    stage(Bt, ldb, n0, (2 * i + 1) * 32, Bs1);
    compute(As0, Bs0);
    __syncthreads();                       // drains DMA -> buf1
    if (i < half - 1) {
      stage(A, lda, m0, (2 * i + 2) * 32, As0);
      stage(Bt, ldb, n0, (2 * i + 2) * 32, Bs0);
    }
    compute(As1, Bs1);
  }

#pragma unroll
  for (int mf = 0; mf < 4; mf++)
#pragma unroll
    for (int nf = 0; nf < 4; nf++) {
      int col = n0 + wn + nf * 16 + l16;
      if (SPLIT_V && col >= 1024) {
        int cc = col - 1024;
        int kvhh = cc >> 7, d = cc & 127;
        int row0 = m0 + wm + mf * 16 + quad * 4;
        int bb = row0 >> 12, s = row0 & 4095;
        ushort4v pv;
        pv.x = f2bf(acc[mf][nf][0]);
        pv.y = f2bf(acc[mf][nf][1]);
        pv.z = f2bf(acc[mf][nf][2]);
        pv.w = f2bf(acc[mf][nf][3]);
        *(ushort4v*)(&vTout[((size_t)((bb * 2 + kvhh) * 128) + d) * 4096 + s]) = pv;
      } else {
#pragma unroll
        for (int r = 0; r < 4; r++) {
          int row = m0 + wm + mf * 16 + quad * 4 + r;
          store_out(C, row * ldc + col, acc[mf][nf][r]);
        }
      }
    }
}

// ---------------- flash attention (segmented, staggered single-buffer) -------
// grid (S/128, H, B*NSEG); 256 thr = 4 waves; 48 KB LDS.
// R9 schedule: B1 / stage_v / QK^T+softmax / B2 / stage_k(i+1) / PV.
// QK^T split into two k-halves (sfr 16 regs); l via ones-MFMA in PV;
// setprio(1) around MFMA clusters.

#define NSEG 4

#define KS_OFF(row, c) (((row) << 7) + ((((c) ^ ((row) & 7))) << 3))
#define VS_OFF(row, c) (((row) << 6) + ((((c) ^ ((row) & 7))) << 3))

__global__ __launch_bounds__(256) void k_attn(const unsigned short* __restrict__ qkv,
                                              const unsigned short* __restrict__ vT,
                                              unsigned short* __restrict__ Opart,
                                              float* __restrict__ lpart) {
  __shared__ __align__(16) unsigned short Ks[64 * 128];   // 16 KB
  __shared__ __align__(16) unsigned short Vt[128 * 64];   // 16 KB
  __shared__ __align__(16) unsigned short Ps[128 * 64];   // 16 KB

  const int qt = blockIdx.x, h = blockIdx.y;
  const int seg = blockIdx.z >> 1, b = blockIdx.z & 1;
  const int kvh = h / 3;
  const int tid = threadIdx.x, w = tid >> 6, lane = tid & 63;
  const int quad = lane >> 4, l16 = lane & 15;

  const char* qbase = (const char*)(qkv + (size_t)(b * 4096) * 1280 + h * 128);
  const char* kbase = (const char*)(qkv + (size_t)(b * 4096) * 1280 + 768 + kvh * 128);
  const char* vtb   = (const char*)(vT + (size_t)((b * 2 + kvh) * 128) * 4096);

  bf16x8 qf[2][4];
  floatx4 acc[2][8] = {};
  floatx4 accl[2] = {};          // l accumulators (ones-MFMA)

  bf16x8 onesf;                  // B-fragment of 1.0 bf16
#pragma unroll
  for (int j = 0; j < 8; j++) onesf[j] = (short)0x3F80;

  // stage Q tile (128x128): rows 0-63 -> Ks, rows 64-127 -> Vt
#pragma unroll
  for (int it = 0; it < 8; it++) {
    int cb = it * 256 + w * 64;
    int j = cb + lane;
    int r = j >> 4, c = (j & 15) ^ (r & 7);
    unsigned short* dst = (cb < 1024) ? &Ks[cb * 8] : &Vt[(cb - 1024) * 8];
    GLOAD_LDS16(qbase + (size_t)(qt * 128 + r) * 2560 + c * 16, dst);
  }
  __syncthreads();

  {
    const unsigned short* qsrc = (w < 2) ? Ks : Vt;
    const int qr0 = (w & 1) * 32;
#pragma unroll
    for (int qg = 0; qg < 2; qg++)
#pragma unroll
      for (int dc = 0; dc < 4; dc++)
        qf[qg][dc] = *(const bf16x8*)(&qsrc[KS_OFF(qr0 + qg * 16 + l16, dc * 4 + quad)]);
  }
  __syncthreads();

  auto stage_k = [&](int kt) {
#pragma unroll
    for (int it = 0; it < 4; it++) {
      int cb = it * 256 + w * 64;
      int j = cb + lane;
      int r = j >> 4, c = (j & 15) ^ (r & 7);
      GLOAD_LDS16(kbase + (size_t)(kt * 64 + r) * 2560 + c * 16, &Ks[cb * 8]);
    }
  };
  auto stage_v = [&](int kt) {
#pragma unroll
    for (int it = 0; it < 4; it++) {
      int cb = it * 256 + w * 64;
      int j = cb + lane;
      int r = j >> 3, c = (j & 7) ^ (r & 7);
      GLOAD_LDS16(vtb + (size_t)r * 8192 + kt * 128 + c * 16, &Vt[cb * 8]);
    }
  };

  const int k0 = seg * 16;
  stage_k(k0);

#pragma unroll 1
  for (int i = 0; i < 16; i++) {
    __syncthreads();             // B1: drains K(i); Vt free
    stage_v(k0 + i);             // V(i) hides under S^T + softmax

    // QK^T + softmax in two k-halves (nf {0,1} then {2,3}); sfr = 16 regs
#pragma unroll
    for (int nfh = 0; nfh < 2; nfh++) {
      floatx4 sfr[2][2] = {};
      __builtin_amdgcn_s_setprio(1);
#pragma unroll
      for (int nfo = 0; nfo < 2; nfo++) {
        int nf = nfh * 2 + nfo;
#pragma unroll
        for (int dc = 0; dc < 4; dc++) {
          bf16x8 kf = *(const bf16x8*)(&Ks[KS_OFF(nf * 16 + l16, dc * 4 + quad)]);
          sfr[0][nfo] = MFMA16(kf, qf[0][dc], sfr[0][nfo]);
          sfr[1][nfo] = MFMA16(kf, qf[1][dc], sfr[1][nfo]);
        }
      }
      __builtin_amdgcn_s_setprio(0);
#pragma unroll
      for (int qg = 0; qg < 2; qg++)
#pragma unroll
        for (int nfo = 0; nfo < 2; nfo++) {
          int nf = nfh * 2 + nfo;
          float p0 = EXP2F(sfr[qg][nfo][0]);
          float p1 = EXP2F(sfr[qg][nfo][1]);
          float p2 = EXP2F(sfr[qg][nfo][2]);
          float p3 = EXP2F(sfr[qg][nfo][3]);
          int row = w * 32 + qg * 16 + l16;
          int ch = nf * 2 + (quad >> 1);
          ushort4v pw;
          pw.x = f2bf_fast(p0);
          pw.y = f2bf_fast(p1);
          pw.z = f2bf_fast(p2);
          pw.w = f2bf_fast(p3);
          *(ushort4v*)(&Ps[VS_OFF(row, ch) + (quad & 1) * 4]) = pw;
        }
    }

    __syncthreads();             // B2: drains V(i); Ks free
    if (i < 15) stage_k(k0 + i + 1);   // K(i+1) hides under PV

    __builtin_amdgcn_s_setprio(1);
#pragma unroll
    for (int kc = 0; kc < 2; kc++) {
      bf16x8 pf0 = *(const bf16x8*)(&Ps[VS_OFF(w * 32 + l16, kc * 4 + quad)]);
      bf16x8 pf1 = *(const bf16x8*)(&Ps[VS_OFF(w * 32 + 16 + l16, kc * 4 + quad)]);
      accl[0] = MFMA16(pf0, onesf, accl[0]);   // l = sum_k P (same bf16 P as PV)
      accl[1] = MFMA16(pf1, onesf, accl[1]);
#pragma unroll
      for (int df = 0; df < 8; df++) {
        bf16x8 vf = *(const bf16x8*)(&Vt[VS_OFF(df * 16 + l16, kc * 4 + quad)]);
        acc[0][df] = MFMA16(pf0, vf, acc[0][df]);
        acc[1][df] = MFMA16(pf1, vf, acc[1][df]);
      }
    }
    __builtin_amdgcn_s_setprio(0);
  }

  // epilogue: UNNORMALIZED partial (bf16) + l (fp32, from ones-MFMA)
  // accl[qg][r] at lane(l16,quad) = l for q-row (w*32 + qg*16 + quad*4 + r),
  // identical across l16 -> write from l16==0 lanes.
  if (l16 == 0) {
#pragma unroll
    for (int qg = 0; qg < 2; qg++)
#pragma unroll
      for (int r = 0; r < 4; r++)
        lpart[((size_t)(seg * 2 + b) * 6 + h) * 4096 + qt * 128 + w * 32 + qg * 16 +
              quad * 4 + r] = accl[qg][r];
  }
#pragma unroll
  for (int qg = 0; qg < 2; qg++) {
#pragma unroll
    for (int r = 0; r < 4; r++) {
      int row = qt * 128 + w * 32 + qg * 16 + quad * 4 + r;
      unsigned short* orow =
          Opart + (size_t)seg * 8192 * 768 + (size_t)(b * 4096 + row) * 768 + h * 128;
#pragma unroll
      for (int df = 0; df < 8; df++)
        orow[df * 16 + l16] = f2bf_fast(acc[qg][df][r]);
    }
  }
}

// ---------------- segment reduce: ob = (sum_s O_s) / (sum_s l_s) ----------------
__global__ __launch_bounds__(256) void k_reduce(const unsigned short* __restrict__ Opart,
                                                const float* __restrict__ lpart,
                                                unsigned short* __restrict__ ob) {
  int idx = (blockIdx.x * 256 + threadIdx.x) * 4;   // < 8192*768
  int row = idx / 768, col = idx - row * 768;
  int h = col >> 7;
  int b = row >> 12, r = row & 4095;

  float lt = 0.f;
#pragma unroll
  for (int s = 0; s < NSEG; s++)
    lt += lpart[((size_t)(s * 2 + b) * 6 + h) * 4096 + r];
  float inv = 1.0f / lt;

  float acc0 = 0.f, acc1 = 0.f, acc2 = 0.f, acc3 = 0.f;
#pragma unroll
  for (int s = 0; s < NSEG; s++) {
    ushort4v v = *(const ushort4v*)(&Opart[(size_t)s * 8192 * 768 + idx]);
    acc0 += bf2f(v.x);
    acc1 += bf2f(v.y);
    acc2 += bf2f(v.z);
    acc3 += bf2f(v.w);
  }
  ushort4v o;
  o.x = f2bf(acc0 * inv);
  o.y = f2bf(acc1 * inv);
  o.z = f2bf(acc2 * inv);
  o.w = f2bf(acc3 * inv);
  *(ushort4v*)(&ob[idx]) = o;
}

// ---------------- launch ----------------

extern "C" void kernel_launch(void* const* d_in, const int* in_sizes, int n_in,
                              void* d_out, int out_size, void* d_ws, size_t ws_size,
                              hipStream_t stream) {
  const float* x  = (const float*)d_in[0];
  const float* wq = (const float*)d_in[1];
  const float* wk = (const float*)d_in[2];
  const float* wv = (const float*)d_in[3];
  const float* wo = (const float*)d_in[4];
  float* out = (float*)d_out;

  char* ws = (char*)d_ws;
  unsigned short* xb    = (unsigned short*)(ws);                 // 12,582,912 B
  unsigned short* wqkvT = (unsigned short*)(ws + 12582912);      //  1,966,080 B
  unsigned short* woT   = (unsigned short*)(ws + 14548992);      //  1,179,648 B
  unsigned short* qkvb  = (unsigned short*)(ws + 15728640);      // 20,971,520 B
  unsigned short* ob    = (unsigned short*)(ws + 36700160);      // 12,582,912 B
  unsigned short* Opart = (unsigned short*)(ws + 49283072);      // 50,331,648 B
  float*          lpart = (float*)(ws + 99614720);               //     786,432 B
  unsigned short* vT    = ob;   // alias: ob dead until k_reduce; vT dead after k_attn
  // total ws use: 100,401,152 B

  k_cvt_x<<<6144, 256, 0, stream>>>(x, xb, 8192 * 768);
  k_cvt_w<<<dim3(12, 32), 256, 0, stream>>>(wq, wk, wv, wo, wqkvT, woT);

  // qkv = xb @ [wq|wk|wv]; V columns written transposed to vT
  k_gemm<unsigned short, true><<<dim3(10, 64), 256, 0, stream>>>(
      xb, 768, wqkvT, 768, qkvb, 1280, 768, vT);

  // attention: 4 KV-segments, unnormalized partials (128 q-rows/block)
  k_attn<<<dim3(32, 6, 2 * NSEG), 256, 0, stream>>>(qkvb, vT, Opart, lpart);

  // merge segments + normalize -> ob (overwrites vT region after k_attn)
  k_reduce<<<6144, 256, 0, stream>>>(Opart, lpart, ob);

  // out = ob @ wo           (M=8192, K=768, N=768), fp32 out
  k_gemm<float, false><<<dim3(6, 64), 256, 0, stream>>>(ob, 768, woT, 768, out, 768, 768, nullptr);
}

// Round 8
// 252.451 us; speedup vs baseline: 1.0735x; 1.0266x over previous
//
#include <hip/hip_runtime.h>

// ---------------------------------------------------------------------------
// BidirectionalAttention: B=2, S=4096, D=768, H=6, KVH=2, HD=128 (GQA x3)
// bf16 MFMA everywhere, fp32 accum.
// R17: R16 minus the ones-MFMA l accumulator. accl[2] (8 AGPR) + onesf
//      (4 VGPR) pushed per-wave unified regs to ~172-176 — just over the
//      ~170 boundary for 3 waves/SIMD (512-reg pool). Reverting l to the
//      rs-add chain (+2 VGPR, cross-quad reduce deferred to epilogue,
//      R13-proven) lands ~158 unified -> 3 blocks/CU NATURALLY (no
//      launch_bounds cap -> no spill risk; LDS 48KB*3=144<=160 OK).
//      Keeps R16's split-half QK^T (sfr 16 regs) + setprio.
// ---------------------------------------------------------------------------

typedef __attribute__((ext_vector_type(8))) short bf16x8;   // 8 bf16 = 4 VGPRs
typedef __attribute__((ext_vector_type(4))) float floatx4;
typedef __attribute__((ext_vector_type(4))) unsigned short ushort4v;

#define MFMA16(a, b, c) __builtin_amdgcn_mfma_f32_16x16x32_bf16((a), (b), (c), 0, 0, 0)

#if __has_builtin(__builtin_amdgcn_exp2f)
#define EXP2F(x) __builtin_amdgcn_exp2f(x)
#else
#define EXP2F(x) exp2f(x)
#endif

#define GLOAD_LDS16(gptr, lptr)                                                   \
  __builtin_amdgcn_global_load_lds(                                               \
      (const __attribute__((address_space(1))) unsigned int*)(gptr),              \
      (__attribute__((address_space(3))) unsigned int*)(lptr), 16, 0, 0)

__device__ __forceinline__ unsigned short f2bf(float f) {   // RNE
  unsigned int u = __builtin_bit_cast(unsigned int, f);
  u = u + 0x7FFFu + ((u >> 16) & 1u);
  return (unsigned short)(u >> 16);
}

__device__ __forceinline__ unsigned short f2bf_fast(float f) {  // round-half-up
  unsigned int u = __builtin_bit_cast(unsigned int, f);
  return (unsigned short)((u + 0x8000u) >> 16);
}

__device__ __forceinline__ float bf2f(unsigned short v) {
  return __builtin_bit_cast(float, (unsigned int)v << 16);
}

// ---------------- convert kernels ----------------

__global__ __launch_bounds__(256) void k_cvt_x(const float* __restrict__ x,
                                               unsigned short* __restrict__ xb, int n) {
  int i = (blockIdx.x * 256 + threadIdx.x) * 4;
  if (i + 3 < n) {
    float4 v = *(const float4*)(x + i);
    xb[i + 0] = f2bf(v.x);
    xb[i + 1] = f2bf(v.y);
    xb[i + 2] = f2bf(v.z);
    xb[i + 3] = f2bf(v.w);
  }
}

// Tiled transpose+convert for all weights. grid (12 kb, 32 nb), 256 thr.
// nb 0-11: wq -> wqkvT rows 0-767 (scaled); 12-15: wk -> rows 768-1023;
// 16-19: wv -> rows 1024-1279; 20-31: wo -> woT rows 0-767.
__global__ __launch_bounds__(256) void k_cvt_w(const float* __restrict__ wq,
                                               const float* __restrict__ wk,
                                               const float* __restrict__ wv,
                                               const float* __restrict__ wo,
                                               unsigned short* __restrict__ wqkvT,
                                               unsigned short* __restrict__ woT) {
  __shared__ float T[64 * 65];
  const float QSCALE = 1.4426950408889634f * 0.08838834764831843f; // log2(e)/sqrt(128)
  const int kb = blockIdx.x, nb = blockIdx.y, tid = threadIdx.x;

  const float* src; int ld, col0; unsigned short* dst; int n0; float scale = 1.0f;
  if (nb < 12)      { src = wq; ld = 768; col0 = nb * 64;        dst = wqkvT; n0 = nb * 64; scale = QSCALE; }
  else if (nb < 16) { src = wk; ld = 256; col0 = (nb - 12) * 64; dst = wqkvT; n0 = nb * 64; }
  else if (nb < 20) { src = wv; ld = 256; col0 = (nb - 16) * 64; dst = wqkvT; n0 = nb * 64; }
  else              { src = wo; ld = 768; col0 = (nb - 20) * 64; dst = woT;   n0 = (nb - 20) * 64; }

  const int k0 = kb * 64;
  {
    int cc = tid & 63, kk0 = tid >> 6;
#pragma unroll
    for (int it = 0; it < 16; it++) {
      int kk = kk0 + it * 4;
      T[kk * 65 + cc] = src[(size_t)(k0 + kk) * ld + col0 + cc] * scale;
    }
  }
  __syncthreads();
  {
    int kk = tid & 63, nn0 = tid >> 6;
#pragma unroll
    for (int it = 0; it < 16; it++) {
      int nn = nn0 + it * 4;
      dst[(size_t)(n0 + nn) * 768 + k0 + kk] = f2bf(T[kk * 65 + nn]);
    }
  }
}

// ---------------- GEMM: C[M,N] = A[M,K] @ Bt[N,K]^T ----------------
// 128x128 tile, BK=32, double-buffered global_load_lds staging (16B DMA,
// chunk swizzle c' = c ^ (r&3) folded into the global source address).
// SPLIT_V: columns >=1024 (V projection) written TRANSPOSED to vTout.

__device__ __forceinline__ void store_out(float* C, int i, float v) { C[i] = v; }
__device__ __forceinline__ void store_out(unsigned short* C, int i, float v) { C[i] = f2bf(v); }

template <typename OUT_T, bool SPLIT_V>
__global__ __launch_bounds__(256) void k_gemm(const unsigned short* __restrict__ A, int lda,
                                              const unsigned short* __restrict__ Bt, int ldb,
                                              OUT_T* __restrict__ C, int ldc, int K,
                                              unsigned short* __restrict__ vTout) {
  __shared__ __align__(16) unsigned short As0[128 * 32];   // 8 KB each
  __shared__ __align__(16) unsigned short As1[128 * 32];
  __shared__ __align__(16) unsigned short Bs0[128 * 32];
  __shared__ __align__(16) unsigned short Bs1[128 * 32];

  const int tid = threadIdx.x;
  const int wave = tid >> 6, lane = tid & 63;
  const int quad = lane >> 4, l16 = lane & 15;
  const int wm = (wave >> 1) * 64, wn = (wave & 1) * 64;
  const int m0 = blockIdx.y * 128, n0 = blockIdx.x * 128;

  floatx4 acc[4][4] = {};

  // stage one 128x32 slice: 512 16B-chunks, 2 per thread; chunk j holds
  // row r = j>>2, col-chunk c = (j&3) ^ (r&3) (swizzle via source address)
  auto stage = [&](const unsigned short* G, int ld, int row0, int k0, unsigned short* S) {
#pragma unroll
    for (int it = 0; it < 2; it++) {
      int j = it * 256 + tid;
      int r = j >> 2, c = (j & 3) ^ (r & 3);
      GLOAD_LDS16((const char*)(G + (size_t)(row0 + r) * ld + k0 + c * 8), &S[j * 8]);
    }
  };

  const int xq = (quad ^ (l16 & 3)) * 8;   // swizzled chunk offset for frags
  auto compute = [&](const unsigned short* As, const unsigned short* Bs) {
    bf16x8 af[4], bfr[4];
#pragma unroll
    for (int mf = 0; mf < 4; mf++)
      af[mf] = *(const bf16x8*)(&As[(wm + mf * 16 + l16) * 32 + xq]);
#pragma unroll
    for (int nf = 0; nf < 4; nf++)
      bfr[nf] = *(const bf16x8*)(&Bs[(wn + nf * 16 + l16) * 32 + xq]);
#pragma unroll
    for (int mf = 0; mf < 4; mf++)
#pragma unroll
      for (int nf = 0; nf < 4; nf++)
        acc[mf][nf] = MFMA16(af[mf], bfr[nf], acc[mf][nf]);
  };

  stage(A, lda, m0, 0, As0);
  stage(Bt, ldb, n0, 0, Bs0);

  const int half = K >> 6;   // K/64 ping-pong pairs (K multiple of 64)
#pragma unroll 1
  for (int i = 0; i < half; i++) {
    __syncthreads();                       // drains DMA -> buf0
    stage(A, lda, m0, (2 * i + 1) * 32, As1);
    stage(Bt, ldb, n0, (2 * i + 1) * 32, Bs1);
    compute(As0, Bs0);
    __syncthreads();                       // drains DMA -> buf1
    if (i < half - 1) {
      stage(A, lda, m0, (2 * i + 2) * 32, As0);
      stage(Bt, ldb, n0, (2 * i + 2) * 32, Bs0);
    }
    compute(As1, Bs1);
  }

#pragma unroll
  for (int mf = 0; mf < 4; mf++)
#pragma unroll
    for (int nf = 0; nf < 4; nf++) {
      int col = n0 + wn + nf * 16 + l16;
      if (SPLIT_V && col >= 1024) {
        int cc = col - 1024;
        int kvhh = cc >> 7, d = cc & 127;
        int row0 = m0 + wm + mf * 16 + quad * 4;
        int bb = row0 >> 12, s = row0 & 4095;
        ushort4v pv;
        pv.x = f2bf(acc[mf][nf][0]);
        pv.y = f2bf(acc[mf][nf][1]);
        pv.z = f2bf(acc[mf][nf][2]);
        pv.w = f2bf(acc[mf][nf][3]);
        *(ushort4v*)(&vTout[((size_t)((bb * 2 + kvhh) * 128) + d) * 4096 + s]) = pv;
      } else {
#pragma unroll
        for (int r = 0; r < 4; r++) {
          int row = m0 + wm + mf * 16 + quad * 4 + r;
          store_out(C, row * ldc + col, acc[mf][nf][r]);
        }
      }
    }
}

// ---------------- flash attention (segmented, staggered single-buffer) -------
// grid (S/128, H, B*NSEG); 256 thr = 4 waves; 48 KB LDS.
// R9 schedule: B1 / stage_v / QK^T+softmax / B2 / stage_k(i+1) / PV.
// QK^T split into two k-halves (sfr 16 regs); l via rs-adds with the
// cross-quad reduce deferred to the epilogue; setprio(1) around MFMA.
// ~158 unified regs/wave -> 3 blocks/CU naturally.

#define NSEG 4

#define KS_OFF(row, c) (((row) << 7) + ((((c) ^ ((row) & 7))) << 3))
#define VS_OFF(row, c) (((row) << 6) + ((((c) ^ ((row) & 7))) << 3))

__global__ __launch_bounds__(256) void k_attn(const unsigned short* __restrict__ qkv,
                                              const unsigned short* __restrict__ vT,
                                              unsigned short* __restrict__ Opart,
                                              float* __restrict__ lpart) {
  __shared__ __align__(16) unsigned short Ks[64 * 128];   // 16 KB
  __shared__ __align__(16) unsigned short Vt[128 * 64];   // 16 KB
  __shared__ __align__(16) unsigned short Ps[128 * 64];   // 16 KB

  const int qt = blockIdx.x, h = blockIdx.y;
  const int seg = blockIdx.z >> 1, b = blockIdx.z & 1;
  const int kvh = h / 3;
  const int tid = threadIdx.x, w = tid >> 6, lane = tid & 63;
  const int quad = lane >> 4, l16 = lane & 15;

  const char* qbase = (const char*)(qkv + (size_t)(b * 4096) * 1280 + h * 128);
  const char* kbase = (const char*)(qkv + (size_t)(b * 4096) * 1280 + 768 + kvh * 128);
  const char* vtb   = (const char*)(vT + (size_t)((b * 2 + kvh) * 128) * 4096);

  bf16x8 qf[2][4];
  floatx4 acc[2][8] = {};
  float l_i[2] = {0.f, 0.f};

  // stage Q tile (128x128): rows 0-63 -> Ks, rows 64-127 -> Vt
#pragma unroll
  for (int it = 0; it < 8; it++) {
    int cb = it * 256 + w * 64;
    int j = cb + lane;
    int r = j >> 4, c = (j & 15) ^ (r & 7);
    unsigned short* dst = (cb < 1024) ? &Ks[cb * 8] : &Vt[(cb - 1024) * 8];
    GLOAD_LDS16(qbase + (size_t)(qt * 128 + r) * 2560 + c * 16, dst);
  }
  __syncthreads();

  {
    const unsigned short* qsrc = (w < 2) ? Ks : Vt;
    const int qr0 = (w & 1) * 32;
#pragma unroll
    for (int qg = 0; qg < 2; qg++)
#pragma unroll
      for (int dc = 0; dc < 4; dc++)
        qf[qg][dc] = *(const bf16x8*)(&qsrc[KS_OFF(qr0 + qg * 16 + l16, dc * 4 + quad)]);
  }
  __syncthreads();

  auto stage_k = [&](int kt) {
#pragma unroll
    for (int it = 0; it < 4; it++) {
      int cb = it * 256 + w * 64;
      int j = cb + lane;
      int r = j >> 4, c = (j & 15) ^ (r & 7);
      GLOAD_LDS16(kbase + (size_t)(kt * 64 + r) * 2560 + c * 16, &Ks[cb * 8]);
    }
  };
  auto stage_v = [&](int kt) {
#pragma unroll
    for (int it = 0; it < 4; it++) {
      int cb = it * 256 + w * 64;
      int j = cb + lane;
      int r = j >> 3, c = (j & 7) ^ (r & 7);
      GLOAD_LDS16(vtb + (size_t)r * 8192 + kt * 128 + c * 16, &Vt[cb * 8]);
    }
  };

  const int k0 = seg * 16;
  stage_k(k0);

#pragma unroll 1
  for (int i = 0; i < 16; i++) {
    __syncthreads();             // B1: drains K(i); Vt free
    stage_v(k0 + i);             // V(i) hides under S^T + softmax

    // QK^T + softmax in two k-halves (nf {0,1} then {2,3}); sfr = 16 regs
#pragma unroll
    for (int nfh = 0; nfh < 2; nfh++) {
      floatx4 sfr[2][2] = {};
      __builtin_amdgcn_s_setprio(1);
#pragma unroll
      for (int nfo = 0; nfo < 2; nfo++) {
        int nf = nfh * 2 + nfo;
#pragma unroll
        for (int dc = 0; dc < 4; dc++) {
          bf16x8 kf = *(const bf16x8*)(&Ks[KS_OFF(nf * 16 + l16, dc * 4 + quad)]);
          sfr[0][nfo] = MFMA16(kf, qf[0][dc], sfr[0][nfo]);
          sfr[1][nfo] = MFMA16(kf, qf[1][dc], sfr[1][nfo]);
        }
      }
      __builtin_amdgcn_s_setprio(0);
#pragma unroll
      for (int qg = 0; qg < 2; qg++)
#pragma unroll
        for (int nfo = 0; nfo < 2; nfo++) {
          int nf = nfh * 2 + nfo;
          float p0 = EXP2F(sfr[qg][nfo][0]);
          float p1 = EXP2F(sfr[qg][nfo][1]);
          float p2 = EXP2F(sfr[qg][nfo][2]);
          float p3 = EXP2F(sfr[qg][nfo][3]);
          l_i[qg] += (p0 + p1) + (p2 + p3);
          int row = w * 32 + qg * 16 + l16;
          int ch = nf * 2 + (quad >> 1);
          ushort4v pw;
          pw.x = f2bf_fast(p0);
          pw.y = f2bf_fast(p1);
          pw.z = f2bf_fast(p2);
          pw.w = f2bf_fast(p3);
          *(ushort4v*)(&Ps[VS_OFF(row, ch) + (quad & 1) * 4]) = pw;
        }
    }

    __syncthreads();             // B2: drains V(i); Ks free
    if (i < 15) stage_k(k0 + i + 1);   // K(i+1) hides under PV

    __builtin_amdgcn_s_setprio(1);
#pragma unroll
    for (int kc = 0; kc < 2; kc++) {
      bf16x8 pf0 = *(const bf16x8*)(&Ps[VS_OFF(w * 32 + l16, kc * 4 + quad)]);
      bf16x8 pf1 = *(const bf16x8*)(&Ps[VS_OFF(w * 32 + 16 + l16, kc * 4 + quad)]);
#pragma unroll
      for (int df = 0; df < 8; df++) {
        bf16x8 vf = *(const bf16x8*)(&Vt[VS_OFF(df * 16 + l16, kc * 4 + quad)]);
        acc[0][df] = MFMA16(pf0, vf, acc[0][df]);
        acc[1][df] = MFMA16(pf1, vf, acc[1][df]);
      }
    }
    __builtin_amdgcn_s_setprio(0);
  }

  // epilogue: UNNORMALIZED partial (bf16) + l (fp32); reduce l across quads
#pragma unroll
  for (int qg = 0; qg < 2; qg++) {
    float lt = l_i[qg];
    lt += __shfl_xor(lt, 16, 64);
    lt += __shfl_xor(lt, 32, 64);
    if (quad == 0)
      lpart[((size_t)(seg * 2 + b) * 6 + h) * 4096 + qt * 128 + w * 32 + qg * 16 + l16] = lt;
#pragma unroll
    for (int r = 0; r < 4; r++) {
      int row = qt * 128 + w * 32 + qg * 16 + quad * 4 + r;
      unsigned short* orow =
          Opart + (size_t)seg * 8192 * 768 + (size_t)(b * 4096 + row) * 768 + h * 128;
#pragma unroll
      for (int df = 0; df < 8; df++)
        orow[df * 16 + l16] = f2bf_fast(acc[qg][df][r]);
    }
  }
}

// ---------------- segment reduce: ob = (sum_s O_s) / (sum_s l_s) ----------------
__global__ __launch_bounds__(256) void k_reduce(const unsigned short* __restrict__ Opart,
                                                const float* __restrict__ lpart,
                                                unsigned short* __restrict__ ob) {
  int idx = (blockIdx.x * 256 + threadIdx.x) * 4;   // < 8192*768
  int row = idx / 768, col = idx - row * 768;
  int h = col >> 7;
  int b = row >> 12, r = row & 4095;

  float lt = 0.f;
#pragma unroll
  for (int s = 0; s < NSEG; s++)
    lt += lpart[((size_t)(s * 2 + b) * 6 + h) * 4096 + r];
  float inv = 1.0f / lt;

  float acc0 = 0.f, acc1 = 0.f, acc2 = 0.f, acc3 = 0.f;
#pragma unroll
  for (int s = 0; s < NSEG; s++) {
    ushort4v v = *(const ushort4v*)(&Opart[(size_t)s * 8192 * 768 + idx]);
    acc0 += bf2f(v.x);
    acc1 += bf2f(v.y);
    acc2 += bf2f(v.z);
    acc3 += bf2f(v.w);
  }
  ushort4v o;
  o.x = f2bf(acc0 * inv);
  o.y = f2bf(acc1 * inv);
  o.z = f2bf(acc2 * inv);
  o.w = f2bf(acc3 * inv);
  *(ushort4v*)(&ob[idx]) = o;
}

// ---------------- launch ----------------

extern "C" void kernel_launch(void* const* d_in, const int* in_sizes, int n_in,
                              void* d_out, int out_size, void* d_ws, size_t ws_size,
                              hipStream_t stream) {
  const float* x  = (const float*)d_in[0];
  const float* wq = (const float*)d_in[1];
  const float* wk = (const float*)d_in[2];
  const float* wv = (const float*)d_in[3];
  const float* wo = (const float*)d_in[4];
  float* out = (float*)d_out;

  char* ws = (char*)d_ws;
  unsigned short* xb    = (unsigned short*)(ws);                 // 12,582,912 B
  unsigned short* wqkvT = (unsigned short*)(ws + 12582912);      //  1,966,080 B
  unsigned short* woT   = (unsigned short*)(ws + 14548992);      //  1,179,648 B
  unsigned short* qkvb  = (unsigned short*)(ws + 15728640);      // 20,971,520 B
  unsigned short* ob    = (unsigned short*)(ws + 36700160);      // 12,582,912 B
  unsigned short* Opart = (unsigned short*)(ws + 49283072);      // 50,331,648 B
  float*          lpart = (float*)(ws + 99614720);               //     786,432 B
  unsigned short* vT    = ob;   // alias: ob dead until k_reduce; vT dead after k_attn
  // total ws use: 100,401,152 B

  k_cvt_x<<<6144, 256, 0, stream>>>(x, xb, 8192 * 768);
  k_cvt_w<<<dim3(12, 32), 256, 0, stream>>>(wq, wk, wv, wo, wqkvT, woT);

  // qkv = xb @ [wq|wk|wv]; V columns written transposed to vT
  k_gemm<unsigned short, true><<<dim3(10, 64), 256, 0, stream>>>(
      xb, 768, wqkvT, 768, qkvb, 1280, 768, vT);

  // attention: 4 KV-segments, unnormalized partials (128 q-rows/block)
  k_attn<<<dim3(32, 6, 2 * NSEG), 256, 0, stream>>>(qkvb, vT, Opart, lpart);

  // merge segments + normalize -> ob (overwrites vT region after k_attn)
  k_reduce<<<6144, 256, 0, stream>>>(Opart, lpart, ob);

  // out = ob @ wo           (M=8192, K=768, N=768), fp32 out
  k_gemm<float, false><<<dim3(6, 64), 256, 0, stream>>>(ob, 768, woT, 768, out, 768, 768, nullptr);
}